// Round 1
// baseline (15052.690 us; speedup 1.0000x reference)
//
#include <hip/hip_runtime.h>
#include <hip/hip_bf16.h>

#define N        2048
#define T_STEPS  8192
#define DIN      64
#define KW       64      // workgroups, 1 per CU (was 128)
#define ROWS     32      // N / KW rows per WG
#define NTHR     512     // 8 waves
#define CAP      320     // padded nonzeros per row (mean 205, sigma 13.6)
#define NNZL     20      // CAP / 16 nonzeros per lane (16-lane row groups)
#define SCOPE_AG __HIP_MEMORY_SCOPE_AGENT

typedef unsigned long long u64;
typedef unsigned int v4u __attribute__((ext_vector_type(4)));

// ---------------------------------------------------------------------------
// Exchange protocol: ex[t&1][k] holds s_t[k] as (fp32_bits<<32)|t — value and
// tag in one naturally-atomic 8-B atom. Producers: one relaxed agent-scope
// 64-bit store. Consumers: 16-B sc1 polls (each 8-B half self-validates via
// its tag; tearing harmless). Depth-2 flow control: a slot can only advance
// to tag t+2 after ALL WGs consumed tag t (the producer's t+2 store is
// program-ordered after its WG's barrier, which requires every thread of
// every WG to have validated tag t) — race-free.
//
// This revision vs previous: (a) masked re-poll — only pending 16-B pairs are
// re-issued while spinning, cutting L3 poll-sweep traffic ~3x; (b) 64 WGs of
// 512 threads — halves the mandatory 2048-value multicast fan-out and the
// producer straggler pool. Per-lane matvec work is unchanged.
// ---------------------------------------------------------------------------

__global__ void init_kernel(u64* ex0) {
    int i = threadIdx.x + blockIdx.x * blockDim.x;
    if (i < N) ex0[i] = 0ull;   // s_0 = 0.0f tagged 0; ex[1] keeps workspace
                                // zeros (tag 0 matches no expected t >= 1).
}

extern "C" __global__ void __launch_bounds__(NTHR, 1)
reservoir_scan(const float* __restrict__ W,
               const float* __restrict__ W_in,
               const float* __restrict__ u,
               const float* __restrict__ noise,
               u64* __restrict__ ex,                 // [2][N] value+tag atoms
               __hip_bfloat16* __restrict__ states)  // [T][N]
{
    __shared__ u64   Wst[8][CAP];     // 20 KB — per-wave 1-row staging (init)
    __shared__ float s_s[2][N];       // 16 KB — double-buffered state
    __shared__ int   s_timeout;

    const int tid = threadIdx.x;
    const int wg  = blockIdx.x;
    const int wv  = tid >> 6;        // wave 0..7
    const int ln  = tid & 63;        // lane 0..63
    const int r0  = wg * ROWS;       // first global row of this WG
    const int l   = ln & 15;         // lane-in-group
    const int g   = ln >> 4;         // row group 0..3
    const int lr  = wv * 4 + g;      // local row this group owns (0..31)
    const int grow = r0 + lr;        // its global row

    u64 wreg[NNZL];

    // --- one-time sparse extraction: each wave ballot-compacts its 4 rows,
    //     one row at a time through a per-wave staging line (keeps LDS small)
    for (int r = 0; r < 4; ++r) {
        const int xlr = wv * 4 + r;
        const size_t rowoff = (size_t)(r0 + xlr) * N;
        int base = 0;
        for (int ch = 0; ch < 32; ++ch) {
            int col = ch * 64 + ln;
            float w = W[rowoff + col];
            u64 m = __ballot(w != 0.0f);
            if (w != 0.0f) {
                int pos = base + (int)__popcll(m & ((1ull << ln) - 1ull));
                if (pos < CAP)
                    Wst[wv][pos] = ((u64)__float_as_uint(w) << 32) | (unsigned)col;
            }
            base += (int)__popcll(m);
        }
        for (int p = base + ln; p < CAP; p += 64)
            Wst[wv][p] = 0ull;        // val=0, col=0 — contributes nothing
        __syncthreads();
        if (g == r) {                 // group r owns row wv*4+r
            #pragma unroll
            for (int i = 0; i < NNZL; ++i)
                wreg[i] = Wst[wv][l + 16 * i];
        }
        __syncthreads();
    }

    // --- input-drive weights: win[j] = W_in[grow][l + 16j] ---
    float win[4];
    #pragma unroll
    for (int j = 0; j < 4; ++j)
        win[j] = W_in[(size_t)grow * DIN + l + 16 * j];

    if (tid == 0) s_timeout = 0;
    __syncthreads();

    // poll addresses: thread covers atoms {2*tid, 2*tid+1} and {+1024 each}
    const u64* ex0a = ex + 2 * tid;          // buffer 0
    const u64* ex1a = ex + N + 2 * tid;      // buffer 1
    u64* wr0 = ex + N + grow;                // store target when buf==0
    u64* wr1 = ex + grow;                    // store target when buf==1

    for (int t = 0; t < T_STEPS; ++t) {
        const int buf = t & 1;

        // independent loads issued early — overlap with the spin-gather
        float ul = u[t * DIN + ln];
        float nz = 0.0f;
        if (l == 0) nz = noise[(size_t)t * N + grow];

        const u64* a0 = buf ? ex1a : ex0a;
        const u64* a1 = a0 + 1024;

        v4u q0, q1;
        unsigned pend = 3u;
        int gd = 0;
        while (pend) {
            // masked re-issue: only pairs still pending hit the fabric again
            if (pend & 1u)
                asm volatile("global_load_dwordx4 %0, %1, off sc1" : "=v"(q0) : "v"(a0));
            if (pend & 2u)
                asm volatile("global_load_dwordx4 %0, %1, off sc1" : "=v"(q1) : "v"(a1));
            asm volatile("s_waitcnt vmcnt(0)" ::: "memory");
            if ((pend & 1u) && q0.x == (unsigned)t && q0.z == (unsigned)t) {
                *(float2*)&s_s[buf][2 * tid] =
                    make_float2(__uint_as_float(q0.y), __uint_as_float(q0.w));
                pend &= ~1u;
            }
            if ((pend & 2u) && q1.x == (unsigned)t && q1.z == (unsigned)t) {
                *(float2*)&s_s[buf][2 * tid + 1024] =
                    make_float2(__uint_as_float(q1.y), __uint_as_float(q1.w));
                pend &= ~2u;
            }
            if (++gd > (1 << 16)) { s_timeout = 1; break; }  // loud abort, no hang
        }

        __syncthreads();          // single barrier per step (s_s is dbuf'd)
        if (s_timeout) return;

        // --- sparse matvec: 20 LDS gathers + 20 FMAs per lane ---
        const float* sb = s_s[buf];
        float acc = 0.0f;
        #pragma unroll
        for (int i = 0; i < NNZL; ++i) {
            unsigned col = (unsigned)wreg[i];
            float    w   = __uint_as_float((unsigned)(wreg[i] >> 32));
            acc += w * sb[col];
        }
        // input drive: Sum_j W_in[grow][l+16j] * u[t][l+16j] via shuffles
        #pragma unroll
        for (int j = 0; j < 4; ++j)
            acc += win[j] * __shfl(ul, l + 16 * j, 64);
        // reduce within the 16-lane group (all 4 rows of the wave at once)
        #pragma unroll
        for (int off = 1; off < 16; off <<= 1)
            acc += __shfl_xor(acc, off, 64);

        if (l == 0) {
            float pre = acc + 0.01f * nz;
            // fast tanh: sign * (1 - 2/(exp2(2*log2e*|x|)+1))
            float ax = __builtin_fabsf(pre);
            float e  = __builtin_amdgcn_exp2f(ax * 2.8853900817779268f);
            float th = 1.0f - 2.0f * __builtin_amdgcn_rcpf(e + 1.0f);
            th = __builtin_copysignf(th, pre);
            float snew = 0.7f * sb[grow] + 0.3f * th;
            u64 pk = ((u64)__float_as_uint(snew) << 32) | (unsigned)(t + 1);
            __hip_atomic_store(buf ? wr1 : wr0, pk, __ATOMIC_RELAXED, SCOPE_AG);
            states[(size_t)t * N + grow] = __float2bfloat16(snew);
        }
        // no trailing barrier: overwriting s_s[buf] at step t+2 requires all
        // WGs' t+1 tags, which data-depend on their reads of s_s[buf].
    }
}

// ---------------------------------------------------------------------------
// readout: out[t][d] = states[t] . w_out[d] + b_out[d].
// ---------------------------------------------------------------------------
__global__ void __launch_bounds__(256)
out_gemm(const __hip_bfloat16* __restrict__ states,
         const float* __restrict__ w_out,
         const float* __restrict__ b_out,
         float* __restrict__ out)
{
    __shared__ float s_lds[4][N];   // 32 KiB
    const int tid = threadIdx.x;
    const int wv  = tid >> 6, ln = tid & 63;
    const int t0  = blockIdx.x * 4;

    for (int idx = tid; idx < 4 * N; idx += 256) {
        int tt = idx >> 11, kk = idx & (N - 1);
        s_lds[tt][kk] = __bfloat162float(states[(size_t)(t0 + tt) * N + kk]);
    }
    __syncthreads();

    const int t = t0 + wv;
    const float4* s4 = (const float4*)&s_lds[wv][0];
    for (int d = 0; d < 64; ++d) {
        const float4* w4 = (const float4*)(w_out + (size_t)d * N);
        float a = 0.0f;
        #pragma unroll
        for (int j = 0; j < 8; ++j) {
            const int ci = ln + 64 * j;
            float4 wv4 = w4[ci];
            float4 sv  = s4[ci];
            a += wv4.x * sv.x + wv4.y * sv.y + wv4.z * sv.z + wv4.w * sv.w;
        }
        #pragma unroll
        for (int off = 1; off < 64; off <<= 1) a += __shfl_xor(a, off, 64);
        if (ln == 0) out[t * 64 + d] = a + b_out[d];
    }
}

// ---------------------------------------------------------------------------
extern "C" void kernel_launch(void* const* d_in, const int* in_sizes, int n_in,
                              void* d_out, int out_size, void* d_ws, size_t ws_size,
                              hipStream_t stream)
{
    const float* u     = (const float*)d_in[0];   // (T, DIN)
    const float* noise = (const float*)d_in[1];   // (T, N)
    const float* W_in  = (const float*)d_in[2];   // (N, DIN)
    const float* W     = (const float*)d_in[3];   // (N, N)
    const float* w_out = (const float*)d_in[4];   // (64, N)
    const float* b_out = (const float*)d_in[5];   // (64,)
    float* out = (float*)d_out;

    // workspace: [0, 32K): ex[2][N] u64 | [64K, 64K+32M): states bf16
    u64* ex                = (u64*)d_ws;
    __hip_bfloat16* states = (__hip_bfloat16*)((char*)d_ws + 65536);

    hipLaunchKernelGGL(init_kernel, dim3((N + 255) / 256), dim3(256), 0, stream,
                       ex);

    void* args[] = { (void*)&W, (void*)&W_in, (void*)&u, (void*)&noise,
                     (void*)&ex, (void*)&states };
    hipLaunchCooperativeKernel((const void*)reservoir_scan,
                               dim3(KW), dim3(NTHR), args, 0, stream);

    hipLaunchKernelGGL(out_gemm, dim3(T_STEPS / 4), dim3(256), 0, stream,
                       states, w_out, b_out, out);
}

// Round 2
// 12826.242 us; speedup vs baseline: 1.1736x; 1.1736x over previous
//
#include <hip/hip_runtime.h>
#include <hip/hip_bf16.h>

#define N        2048
#define T_STEPS  8192
#define DIN      64
#define KW       256     // 128 primary WGs + 128 mirror WGs (1 per CU)
#define NPRIM    128     // primaries; mirror m covers primary ((m-128+4)&127)
#define ROWS     16      // N / NPRIM rows per WG
#define NTHR     256
#define CAP      320     // padded nonzeros per row (mean 205, sigma 13.6)
#define NNZL     20      // CAP / 16 nonzeros per lane (16-lane row groups)
#define SCOPE_AG __HIP_MEMORY_SCOPE_AGENT

typedef unsigned long long u64;
typedef unsigned int v4u __attribute__((ext_vector_type(4)));

// ---------------------------------------------------------------------------
// Exchange protocol: ex[t&1][k] holds s_t[k] as (fp32_bits<<32)|t — value and
// tag in one naturally-atomic 8-B atom. Producers: one relaxed agent-scope
// 64-bit store. Consumers: 16-B sc1 polls (each 8-B half self-validates via
// its tag; tearing harmless). Depth-2 flow control: a slot advances to tag
// t+2 only after the storer consumed t+1, which transitively requires every
// surviving producer chain to have consumed t — race-free.
//
// This revision: TWIN REDUNDANCY. Every row is produced by two WGs on
// different XCDs computing bit-identical values (benign duplicate stores).
// Per-step publish time per row = min of two independent stragglers, which
// collapses the max-over-rows tail that sets the global step period. A twin
// that gets lapped (observes tag > expected: its row partner outran it by a
// full depth-2 cycle) exits WG-uniformly; the last-standing producer of a
// row can never be lapped (its consumption gates the frontier), so coverage
// is preserved. Both twins write states[] so output is complete even if one
// exits at any step.
// ---------------------------------------------------------------------------

__global__ void init_kernel(u64* ex) {
    int i = threadIdx.x + blockIdx.x * blockDim.x;
    if (i < 2 * N) ex[i] = 0ull;  // buf0: s_0 = 0.0f tagged 0 (valid at t=0)
                                  // buf1: tag 0 < 1 — spins, never "overtake"
}

extern "C" __global__ void __launch_bounds__(NTHR, 1)
reservoir_scan(const float* __restrict__ W,
               const float* __restrict__ W_in,
               const float* __restrict__ u,
               const float* __restrict__ noise,
               u64* __restrict__ ex,                 // [2][N] value+tag atoms
               __hip_bfloat16* __restrict__ states)  // [T][N]
{
    __shared__ u64   Wp[ROWS][CAP];   // 40 KB — sparse staging (init only)
    __shared__ float s_s[2][N];       // 16 KB — double-buffered state
    __shared__ int   s_exit;

    const int tid = threadIdx.x;
    const int wg  = blockIdx.x;
    // mirror WGs cover primary (wg-128+4)&127: +4 (mod 8) => different XCD
    const int pi  = (wg < NPRIM) ? wg : ((wg - NPRIM + 4) & (NPRIM - 1));
    const int wv  = tid >> 6;        // wave 0..3
    const int ln  = tid & 63;        // lane 0..63
    const int r0  = pi * ROWS;       // first global row of this WG
    const int l   = ln & 15;         // lane-in-group
    const int g   = ln >> 4;         // row group 0..3
    const int lr  = wv * 4 + g;      // local row this group owns
    const int grow = r0 + lr;        // its global row

    // --- one-time sparse extraction: ballot-compact this wave's 4 rows ---
    for (int r = 0; r < 4; ++r) {
        const int xlr = wv * 4 + r;
        const size_t rowoff = (size_t)(r0 + xlr) * N;
        int base = 0;
        for (int ch = 0; ch < 32; ++ch) {
            int col = ch * 64 + ln;
            float w = W[rowoff + col];
            u64 m = __ballot(w != 0.0f);
            if (w != 0.0f) {
                int pos = base + (int)__popcll(m & ((1ull << ln) - 1ull));
                if (pos < CAP)
                    Wp[xlr][pos] = ((u64)__float_as_uint(w) << 32) | (unsigned)col;
            }
            base += (int)__popcll(m);
        }
        for (int p = base + ln; p < CAP; p += 64)
            Wp[xlr][p] = 0ull;        // val=0, col=0 — contributes nothing
    }
    if (tid == 0) s_exit = 0;
    __syncthreads();

    // --- sparse slice to registers: lane (g,l) takes row lr's slots l+16i ---
    u64 wreg[NNZL];
    #pragma unroll
    for (int i = 0; i < NNZL; ++i)
        wreg[i] = Wp[lr][l + 16 * i];

    // --- input-drive weights: win[j] = W_in[grow][l + 16j] ---
    float win[4];
    #pragma unroll
    for (int j = 0; j < 4; ++j)
        win[j] = W_in[(size_t)grow * DIN + l + 16 * j];
    __syncthreads();   // Wp dead from here

    // this thread's 4 atom-pairs for polling: p_i = wv*256 + 64i + ln
    const int p0 = wv * 256 + ln;

    for (int t = 0; t < T_STEPS; ++t) {
        const int buf = t & 1;

        // independent loads issued early — overlap with the spin-gather
        float ul = u[t * DIN + ln];
        float nz = 0.0f;
        if (l == 0) nz = noise[(size_t)t * N + grow];

        u64* exb = ex + (size_t)buf * N;
        const u64* a0 = exb + 2 * (p0);
        const u64* a1 = exb + 2 * (p0 + 64);
        const u64* a2 = exb + 2 * (p0 + 128);
        const u64* a3 = exb + 2 * (p0 + 192);
        v4u q0, q1, q2, q3;
        const unsigned tu = (unsigned)t;
        bool good = false;
        int gd = 0;
        for (;;) {
            asm volatile("global_load_dwordx4 %0, %1, off sc1" : "=v"(q0) : "v"(a0));
            asm volatile("global_load_dwordx4 %0, %1, off sc1" : "=v"(q1) : "v"(a1));
            asm volatile("global_load_dwordx4 %0, %1, off sc1" : "=v"(q2) : "v"(a2));
            asm volatile("global_load_dwordx4 %0, %1, off sc1" : "=v"(q3) : "v"(a3));
            asm volatile("s_waitcnt vmcnt(0)" ::: "memory");
            int ok = (q0.x == tu) + (q0.z == tu)
                   + (q1.x == tu) + (q1.z == tu)
                   + (q2.x == tu) + (q2.z == tu)
                   + (q3.x == tu) + (q3.z == tu);
            int ov = (q0.x > tu) | (q0.z > tu)
                   | (q1.x > tu) | (q1.z > tu)
                   | (q2.x > tu) | (q2.z > tu)
                   | (q3.x > tu) | (q3.z > tu);
            if (__any(ov) || ++gd > (1 << 17)) { s_exit = 1; break; } // lapped
            if (__all(ok == 8)) { good = true; break; }
        }
        if (good) {
            *(float2*)&s_s[buf][2 * (p0      )] = make_float2(__uint_as_float(q0.y), __uint_as_float(q0.w));
            *(float2*)&s_s[buf][2 * (p0 +  64)] = make_float2(__uint_as_float(q1.y), __uint_as_float(q1.w));
            *(float2*)&s_s[buf][2 * (p0 + 128)] = make_float2(__uint_as_float(q2.y), __uint_as_float(q2.w));
            *(float2*)&s_s[buf][2 * (p0 + 192)] = make_float2(__uint_as_float(q3.y), __uint_as_float(q3.w));
        }

        __syncthreads();          // single barrier per step (s_s is dbuf'd)
        if (s_exit) return;       // WG-uniform retirement: twin covers rows

        // --- sparse matvec: 20 LDS gathers + 20 FMAs per lane ---
        float acc = 0.0f;
        #pragma unroll
        for (int i = 0; i < NNZL; ++i) {
            unsigned col = (unsigned)wreg[i];
            float    w   = __uint_as_float((unsigned)(wreg[i] >> 32));
            acc += w * s_s[buf][col];
        }
        // input drive: Sum_j W_in[grow][l+16j] * u[t][l+16j] via shuffles
        #pragma unroll
        for (int j = 0; j < 4; ++j)
            acc += win[j] * __shfl(ul, l + 16 * j, 64);
        // reduce within the 16-lane group (all 4 rows of the wave at once)
        #pragma unroll
        for (int off = 1; off < 16; off <<= 1)
            acc += __shfl_xor(acc, off, 64);

        if (l == 0) {
            float pre = acc + 0.01f * nz;
            // fast tanh: sign * (1 - 2/(exp2(2*log2e*|x|)+1))
            float ax = __builtin_fabsf(pre);
            float e  = __builtin_amdgcn_exp2f(ax * 2.8853900817779268f);
            float th = 1.0f - 2.0f * __builtin_amdgcn_rcpf(e + 1.0f);
            th = __builtin_copysignf(th, pre);
            float snew = 0.7f * s_s[buf][grow] + 0.3f * th;
            u64 pk = ((u64)__float_as_uint(snew) << 32) | (unsigned)(t + 1);
            // benign race: twin stores the bit-identical atom
            __hip_atomic_store(&ex[(size_t)(buf ^ 1) * N + grow], pk,
                               __ATOMIC_RELAXED, SCOPE_AG);
            // both twins write (required: a retired twin must be covered)
            states[(size_t)t * N + grow] = __float2bfloat16(snew);
        }
        // no trailing barrier: overwriting s_s[buf] at step t+2 requires all
        // surviving WGs' t+1 tags, which data-depend on their reads of s_s[buf].
    }
}

// ---------------------------------------------------------------------------
// readout: out[t][d] = states[t] . w_out[d] + b_out[d].
// ---------------------------------------------------------------------------
__global__ void __launch_bounds__(256)
out_gemm(const __hip_bfloat16* __restrict__ states,
         const float* __restrict__ w_out,
         const float* __restrict__ b_out,
         float* __restrict__ out)
{
    __shared__ float s_lds[4][N];   // 32 KiB
    const int tid = threadIdx.x;
    const int wv  = tid >> 6, ln = tid & 63;
    const int t0  = blockIdx.x * 4;

    for (int idx = tid; idx < 4 * N; idx += 256) {
        int tt = idx >> 11, kk = idx & (N - 1);
        s_lds[tt][kk] = __bfloat162float(states[(size_t)(t0 + tt) * N + kk]);
    }
    __syncthreads();

    const int t = t0 + wv;
    const float4* s4 = (const float4*)&s_lds[wv][0];
    for (int d = 0; d < 64; ++d) {
        const float4* w4 = (const float4*)(w_out + (size_t)d * N);
        float a = 0.0f;
        #pragma unroll
        for (int j = 0; j < 8; ++j) {
            const int ci = ln + 64 * j;
            float4 wv4 = w4[ci];
            float4 sv  = s4[ci];
            a += wv4.x * sv.x + wv4.y * sv.y + wv4.z * sv.z + wv4.w * sv.w;
        }
        #pragma unroll
        for (int off = 1; off < 64; off <<= 1) a += __shfl_xor(a, off, 64);
        if (ln == 0) out[t * 64 + d] = a + b_out[d];
    }
}

// ---------------------------------------------------------------------------
extern "C" void kernel_launch(void* const* d_in, const int* in_sizes, int n_in,
                              void* d_out, int out_size, void* d_ws, size_t ws_size,
                              hipStream_t stream)
{
    const float* u     = (const float*)d_in[0];   // (T, DIN)
    const float* noise = (const float*)d_in[1];   // (T, N)
    const float* W_in  = (const float*)d_in[2];   // (N, DIN)
    const float* W     = (const float*)d_in[3];   // (N, N)
    const float* w_out = (const float*)d_in[4];   // (64, N)
    const float* b_out = (const float*)d_in[5];   // (64,)
    float* out = (float*)d_out;

    // workspace: [0, 32K): ex[2][N] u64 | [64K, 64K+32M): states bf16
    u64* ex                = (u64*)d_ws;
    __hip_bfloat16* states = (__hip_bfloat16*)((char*)d_ws + 65536);

    hipLaunchKernelGGL(init_kernel, dim3((2 * N + 255) / 256), dim3(256), 0,
                       stream, ex);

    void* args[] = { (void*)&W, (void*)&W_in, (void*)&u, (void*)&noise,
                     (void*)&ex, (void*)&states };
    hipLaunchCooperativeKernel((const void*)reservoir_scan,
                               dim3(KW), dim3(NTHR), args, 0, stream);

    hipLaunchKernelGGL(out_gemm, dim3(T_STEPS / 4), dim3(256), 0, stream,
                       states, w_out, b_out, out);
}

// Round 3
// 12227.359 us; speedup vs baseline: 1.2311x; 1.0490x over previous
//
#include <hip/hip_runtime.h>
#include <hip/hip_bf16.h>

#define N        2048
#define T_STEPS  8192
#define DIN      64
#define KW       128     // workgroups, 1 per CU
#define ROWS     16      // N / KW rows per WG
#define NTHR     256
#define CAP      320     // padded nonzeros per row (mean 205, sigma 13.6)
#define NNZL     20      // CAP / 16 nonzeros per lane (16-lane row groups)
#define SCOPE_AG __HIP_MEMORY_SCOPE_AGENT

typedef unsigned long long u64;
typedef unsigned int v4u __attribute__((ext_vector_type(4)));

// ---------------------------------------------------------------------------
// Exchange protocol: ex[t&1][k] holds s_t[k] as (fp32_bits<<32)|t — value and
// tag in one naturally-atomic 8-B atom. Depth-2 flow control: a slot can only
// advance to tag t+2 after ALL WGs consumed tag t (race-free).
//
// This revision: producers publish via ATOMIC SWAP (no-return) instead of a
// relaxed sc1 store. Theory: the sc1 store path is write-through/invalidate —
// WRITE_SIZE showed exactly 16 KB/step of exchange written outward, and the
// measured 3500-cy step period matches a chain of HBM-class round trips. An
// atomic RMW executes AT the device coherence point and leaves the line
// resident there, so consumer sc1 polls should hit MALL (~600 cy) instead of
// HBM (~1600 cy), shortening the per-step latency chain.
// ---------------------------------------------------------------------------

__global__ void init_kernel(u64* ex) {
    int i = threadIdx.x + blockIdx.x * blockDim.x;
    if (i < 2 * N) ex[i] = 0ull;  // buf0: s_0 = 0.0f tagged 0 (valid at t=0)
                                  // buf1: tag 0 — no poll ever matches it
                                  // before the first t=1 publish lands.
}

extern "C" __global__ void __launch_bounds__(NTHR, 1)
reservoir_scan(const float* __restrict__ W,
               const float* __restrict__ W_in,
               const float* __restrict__ u,
               const float* __restrict__ noise,
               u64* __restrict__ ex,                 // [2][N] value+tag atoms
               __hip_bfloat16* __restrict__ states)  // [T][N]
{
    __shared__ u64   Wp[ROWS][CAP];   // 40 KB — sparse staging (init only)
    __shared__ float s_s[2][N];       // 16 KB — double-buffered state
    __shared__ int   s_timeout;

    const int tid = threadIdx.x;
    const int wg  = blockIdx.x;
    const int wv  = tid >> 6;        // wave 0..3
    const int ln  = tid & 63;        // lane 0..63
    const int r0  = wg * ROWS;       // first global row of this WG
    const int l   = ln & 15;         // lane-in-group
    const int g   = ln >> 4;         // row group 0..3
    const int lr  = wv * 4 + g;      // local row this group owns
    const int grow = r0 + lr;        // its global row

    // --- one-time sparse extraction: ballot-compact this wave's 4 rows ---
    for (int r = 0; r < 4; ++r) {
        const int xlr = wv * 4 + r;
        const size_t rowoff = (size_t)(r0 + xlr) * N;
        int base = 0;
        for (int ch = 0; ch < 32; ++ch) {
            int col = ch * 64 + ln;
            float w = W[rowoff + col];
            u64 m = __ballot(w != 0.0f);
            if (w != 0.0f) {
                int pos = base + (int)__popcll(m & ((1ull << ln) - 1ull));
                if (pos < CAP)
                    Wp[xlr][pos] = ((u64)__float_as_uint(w) << 32) | (unsigned)col;
            }
            base += (int)__popcll(m);
        }
        for (int p = base + ln; p < CAP; p += 64)
            Wp[xlr][p] = 0ull;        // val=0, col=0 — contributes nothing
    }
    if (tid == 0) s_timeout = 0;
    __syncthreads();

    // --- sparse slice to registers: lane (g,l) takes row lr's slots l+16i ---
    u64 wreg[NNZL];
    #pragma unroll
    for (int i = 0; i < NNZL; ++i)
        wreg[i] = Wp[lr][l + 16 * i];

    // --- input-drive weights: win[j] = W_in[grow][l + 16j] ---
    float win[4];
    #pragma unroll
    for (int j = 0; j < 4; ++j)
        win[j] = W_in[(size_t)grow * DIN + l + 16 * j];
    __syncthreads();   // Wp dead from here

    // this thread's 4 atom-pairs for polling: p_i = wv*256 + 64i + ln
    const int p0 = wv * 256 + ln;

    for (int t = 0; t < T_STEPS; ++t) {
        const int buf = t & 1;

        // independent loads issued early — overlap with the spin-gather
        float ul = u[t * DIN + ln];
        float nz = 0.0f;
        if (l == 0) nz = noise[(size_t)t * N + grow];

        u64* exb = ex + (size_t)buf * N;
        const u64* a0 = exb + 2 * (p0);
        const u64* a1 = exb + 2 * (p0 + 64);
        const u64* a2 = exb + 2 * (p0 + 128);
        const u64* a3 = exb + 2 * (p0 + 192);
        v4u q0, q1, q2, q3;
        const unsigned tu = (unsigned)t;
        bool good = false;
        int gd = 0;
        for (;;) {
            asm volatile("global_load_dwordx4 %0, %1, off sc1" : "=v"(q0) : "v"(a0));
            asm volatile("global_load_dwordx4 %0, %1, off sc1" : "=v"(q1) : "v"(a1));
            asm volatile("global_load_dwordx4 %0, %1, off sc1" : "=v"(q2) : "v"(a2));
            asm volatile("global_load_dwordx4 %0, %1, off sc1" : "=v"(q3) : "v"(a3));
            asm volatile("s_waitcnt vmcnt(0)" ::: "memory");
            int ok = (q0.x == tu) + (q0.z == tu)
                   + (q1.x == tu) + (q1.z == tu)
                   + (q2.x == tu) + (q2.z == tu)
                   + (q3.x == tu) + (q3.z == tu);
            if (__all(ok == 8)) { good = true; break; }
            if (++gd > (1 << 17)) { s_timeout = 1; break; }  // loud abort
        }
        if (good) {
            *(float2*)&s_s[buf][2 * (p0      )] = make_float2(__uint_as_float(q0.y), __uint_as_float(q0.w));
            *(float2*)&s_s[buf][2 * (p0 +  64)] = make_float2(__uint_as_float(q1.y), __uint_as_float(q1.w));
            *(float2*)&s_s[buf][2 * (p0 + 128)] = make_float2(__uint_as_float(q2.y), __uint_as_float(q2.w));
            *(float2*)&s_s[buf][2 * (p0 + 192)] = make_float2(__uint_as_float(q3.y), __uint_as_float(q3.w));
        }

        __syncthreads();          // single barrier per step (s_s is dbuf'd)
        if (s_timeout) return;    // uniform abort instead of an eternal hang

        // --- sparse matvec: 20 LDS gathers + 20 FMAs per lane ---
        float acc = 0.0f;
        #pragma unroll
        for (int i = 0; i < NNZL; ++i) {
            unsigned col = (unsigned)wreg[i];
            float    w   = __uint_as_float((unsigned)(wreg[i] >> 32));
            acc += w * s_s[buf][col];
        }
        // input drive: Sum_j W_in[grow][l+16j] * u[t][l+16j] via shuffles
        #pragma unroll
        for (int j = 0; j < 4; ++j)
            acc += win[j] * __shfl(ul, l + 16 * j, 64);
        // reduce within the 16-lane group (all 4 rows of the wave at once)
        #pragma unroll
        for (int off = 1; off < 16; off <<= 1)
            acc += __shfl_xor(acc, off, 64);

        if (l == 0) {
            float pre = acc + 0.01f * nz;
            // fast tanh: sign * (1 - 2/(exp2(2*log2e*|x|)+1))
            float ax = __builtin_fabsf(pre);
            float e  = __builtin_amdgcn_exp2f(ax * 2.8853900817779268f);
            float th = 1.0f - 2.0f * __builtin_amdgcn_rcpf(e + 1.0f);
            th = __builtin_copysignf(th, pre);
            float snew = 0.7f * s_s[buf][grow] + 0.3f * th;
            u64 pk = ((u64)__float_as_uint(snew) << 32) | (unsigned)(t + 1);
            // PUBLISH VIA ATOMIC SWAP (no-return): executes at the device
            // coherence point and leaves the line resident there, so the
            // consumers' sc1 polls hit cache instead of HBM.
            (void)__hip_atomic_exchange(&ex[(size_t)(buf ^ 1) * N + grow], pk,
                                        __ATOMIC_RELAXED, SCOPE_AG);
            states[(size_t)t * N + grow] = __float2bfloat16(snew);
        }
        // no trailing barrier: overwriting s_s[buf] at step t+2 requires all
        // WGs' t+1 tags, which data-depend on their reads of s_s[buf].
    }
}

// ---------------------------------------------------------------------------
// readout: out[t][d] = states[t] . w_out[d] + b_out[d].
// ---------------------------------------------------------------------------
__global__ void __launch_bounds__(256)
out_gemm(const __hip_bfloat16* __restrict__ states,
         const float* __restrict__ w_out,
         const float* __restrict__ b_out,
         float* __restrict__ out)
{
    __shared__ float s_lds[4][N];   // 32 KiB
    const int tid = threadIdx.x;
    const int wv  = tid >> 6, ln = tid & 63;
    const int t0  = blockIdx.x * 4;

    for (int idx = tid; idx < 4 * N; idx += 256) {
        int tt = idx >> 11, kk = idx & (N - 1);
        s_lds[tt][kk] = __bfloat162float(states[(size_t)(t0 + tt) * N + kk]);
    }
    __syncthreads();

    const int t = t0 + wv;
    const float4* s4 = (const float4*)&s_lds[wv][0];
    for (int d = 0; d < 64; ++d) {
        const float4* w4 = (const float4*)(w_out + (size_t)d * N);
        float a = 0.0f;
        #pragma unroll
        for (int j = 0; j < 8; ++j) {
            const int ci = ln + 64 * j;
            float4 wv4 = w4[ci];
            float4 sv  = s4[ci];
            a += wv4.x * sv.x + wv4.y * sv.y + wv4.z * sv.z + wv4.w * sv.w;
        }
        #pragma unroll
        for (int off = 1; off < 64; off <<= 1) a += __shfl_xor(a, off, 64);
        if (ln == 0) out[t * 64 + d] = a + b_out[d];
    }
}

// ---------------------------------------------------------------------------
extern "C" void kernel_launch(void* const* d_in, const int* in_sizes, int n_in,
                              void* d_out, int out_size, void* d_ws, size_t ws_size,
                              hipStream_t stream)
{
    const float* u     = (const float*)d_in[0];   // (T, DIN)
    const float* noise = (const float*)d_in[1];   // (T, N)
    const float* W_in  = (const float*)d_in[2];   // (N, DIN)
    const float* W     = (const float*)d_in[3];   // (N, N)
    const float* w_out = (const float*)d_in[4];   // (64, N)
    const float* b_out = (const float*)d_in[5];   // (64,)
    float* out = (float*)d_out;

    // workspace: [0, 32K): ex[2][N] u64 | [64K, 64K+32M): states bf16
    u64* ex                = (u64*)d_ws;
    __hip_bfloat16* states = (__hip_bfloat16*)((char*)d_ws + 65536);

    hipLaunchKernelGGL(init_kernel, dim3((2 * N + 255) / 256), dim3(256), 0,
                       stream, ex);

    void* args[] = { (void*)&W, (void*)&W_in, (void*)&u, (void*)&noise,
                     (void*)&ex, (void*)&states };
    hipLaunchCooperativeKernel((const void*)reservoir_scan,
                               dim3(KW), dim3(NTHR), args, 0, stream);

    hipLaunchKernelGGL(out_gemm, dim3(T_STEPS / 4), dim3(256), 0, stream,
                       states, w_out, b_out, out);
}